// Round 2
// baseline (6511.355 us; speedup 1.0000x reference)
//
#include <hip/hip_runtime.h>
#include <math.h>

// Problem constants
#define BB 16
#define DD 40
#define NN 64512
#define KK 4
#define ALPHA 5.0f
#define N_ITERS 10
#define EPS_KM 1e-9f

#define NQ (NN / 4)                 // 16128 float4 per row
#define MASK_FLOATS (BB * KK * NN)  // 4128768
#define SLOT_FLOATS (BB * KK * DD + BB * KK)  // 2624: accV[2560] + accS[64]
// Scratch layout inside the mask region of d_out:
//   v2:   [0, BB*NN)                      = 1032192 floats
//   acc:  [BB*NN, BB*NN + 11*SLOT_FLOATS) = slots 0..10
#define ACC_OFF (BB * NN)

// ---------------------------------------------------------------------------
// Zero the 10 output accumulator slots (1..10). Slot 0 is written by init.
// ---------------------------------------------------------------------------
__global__ __launch_bounds__(256) void zero_kernel(float* __restrict__ p, int n) {
    int i = blockIdx.x * 256 + threadIdx.x;
    if (i < n) p[i] = 0.f;
}

// ---------------------------------------------------------------------------
// Fused: Vact = tanh(V), v2[b][n] = sum_d Vact^2. Block (c,b): 1024 n's, loops d.
// ---------------------------------------------------------------------------
__global__ __launch_bounds__(256) void tanhv2_kernel(const float4* __restrict__ V,
                                                     float4* __restrict__ Vact,
                                                     float4* __restrict__ v2out) {
    const int b = blockIdx.y;
    const int j = blockIdx.x * 256 + threadIdx.x;  // float4 column, [0, 16128)
    const float4* Vb = V + (size_t)b * DD * NQ + j;
    float4* Ab = Vact + (size_t)b * DD * NQ + j;
    float4 s = {0.f, 0.f, 0.f, 0.f};
#pragma unroll 8
    for (int d = 0; d < DD; ++d) {
        float4 x = Vb[(size_t)d * NQ];
        float4 y;
        y.x = tanhf(x.x); y.y = tanhf(x.y); y.z = tanhf(x.z); y.w = tanhf(x.w);
        Ab[(size_t)d * NQ] = y;
        s.x = fmaf(y.x, y.x, s.x); s.y = fmaf(y.y, y.y, s.y);
        s.z = fmaf(y.z, y.z, s.z); s.w = fmaf(y.w, y.w, s.w);
    }
    v2out[(size_t)b * NQ + j] = s;
}

// ---------------------------------------------------------------------------
// Init slot 0: accV0[b,k,d] = tanh(V[b,d,idx[b,k]]), accS0 = 1.0
// (km_iter divides by accS+eps, so U0 = tanh(...)/(1+1e-9) — negligible.)
// ---------------------------------------------------------------------------
__global__ __launch_bounds__(256) void init_kernel(const float* __restrict__ V,
                                                   const int* __restrict__ idx,
                                                   float* __restrict__ accV0,
                                                   float* __restrict__ accS0) {
    const int tid = threadIdx.x;
    for (int i = tid; i < BB * KK * DD; i += 256) {
        int b = i / (KK * DD);
        int r = i - b * (KK * DD);
        int k = r / DD;
        int d = r - k * DD;
        int n0 = idx[b * KK + k];
        accV0[i] = tanhf(V[((size_t)b * DD + d) * NN + n0]);
    }
    if (tid < BB * KK) accS0[tid] = 1.0f;
}

// ---------------------------------------------------------------------------
// One k-means iteration. grid (126, BB); block 256 = 4 waves.
// Wave w owns d-slice [10w, 10w+10). Each block: 512 n's = 8 steps of 64.
// Prologue computes U = accVp/(accSp+eps) and u2 in LDS.
// Main loop: prefetched loads + ping-pong LDS partial exchange, 1 barrier/step.
// ---------------------------------------------------------------------------
__global__ __launch_bounds__(256, 3) void km_iter_kernel(
    const float* __restrict__ Vact, const float* __restrict__ v2g,
    const float* __restrict__ accVp, const float* __restrict__ accSp,
    float* __restrict__ accVn, float* __restrict__ accSn) {
    __shared__ float sU[KK * DD];
    __shared__ float su2[KK];
    __shared__ float4 part[2][4][64];

    const int tid = threadIdx.x;
    const int w = tid >> 6;
    const int l = tid & 63;
    const int b = blockIdx.y;

    if (tid < KK * DD) {
        int k = tid / DD;
        sU[tid] = accVp[b * KK * DD + tid] / (accSp[b * KK + k] + EPS_KM);
    }
    __syncthreads();
    if (tid < KK) {
        float s = 0.f;
        for (int d = 0; d < DD; ++d) {
            float x = sU[tid * DD + d];
            s = fmaf(x, x, s);
        }
        su2[tid] = s;
    }
    __syncthreads();

    const int d0 = w * 10;
    float uk[KK][10];
    float u2r[KK];
#pragma unroll
    for (int k = 0; k < KK; ++k) {
#pragma unroll
        for (int j = 0; j < 10; ++j) uk[k][j] = sU[k * DD + d0 + j];
        u2r[k] = su2[k];
    }

    float acc[KK][10];
#pragma unroll
    for (int k = 0; k < KK; ++k)
#pragma unroll
        for (int j = 0; j < 10; ++j) acc[k][j] = 0.f;
    float sy[KK] = {0.f, 0.f, 0.f, 0.f};

    const float* Vb = Vact + (size_t)b * DD * NN + (size_t)d0 * NN;
    const float* v2b = v2g + (size_t)b * NN;
    const int nb = blockIdx.x * 512 + l;

    float vC[10], vN[10], v2C, v2N;
#pragma unroll
    for (int j = 0; j < 10; ++j) vC[j] = Vb[(size_t)j * NN + nb];
    v2C = v2b[nb];
    {
        float p0 = 0.f, p1 = 0.f, p2 = 0.f, p3 = 0.f;
#pragma unroll
        for (int j = 0; j < 10; ++j) {
            const float vv = vC[j];
            p0 = fmaf(uk[0][j], vv, p0);
            p1 = fmaf(uk[1][j], vv, p1);
            p2 = fmaf(uk[2][j], vv, p2);
            p3 = fmaf(uk[3][j], vv, p3);
        }
        part[0][w][l] = make_float4(p0, p1, p2, p3);
    }
    __syncthreads();

#pragma unroll
    for (int s = 0; s < 8; ++s) {
        const int cur = s & 1;
        // prefetch next step's v (issued before consuming current partials)
        if (s < 7) {
            const int n = nb + (s + 1) * 64;
#pragma unroll
            for (int j = 0; j < 10; ++j) vN[j] = Vb[(size_t)j * NN + n];
            v2N = v2b[n];
        }
        // gather cross-wave partials for this step
        float4 q0 = part[cur][0][l];
        float4 q1 = part[cur][1][l];
        float4 q2 = part[cur][2][l];
        float4 q3 = part[cur][3][l];
        float c[KK];
        c[0] = (q0.x + q1.x) + (q2.x + q3.x);
        c[1] = (q0.y + q1.y) + (q2.y + q3.y);
        c[2] = (q0.z + q1.z) + (q2.z + q3.z);
        c[3] = (q0.w + q1.w) + (q2.w + q3.w);

        float dist[KK];
        float m = -1e30f;
#pragma unroll
        for (int k = 0; k < KK; ++k) {
            float d2 = v2C + u2r[k] - 2.f * c[k];
            dist[k] = -ALPHA * sqrtf(fmaxf(d2, 1e-12f));
            m = fmaxf(m, dist[k]);
        }
        float e[KK];
        float se = 0.f;
#pragma unroll
        for (int k = 0; k < KK; ++k) {
            e[k] = __expf(dist[k] - m);
            se += e[k];
        }
        const float inv = 1.f / se;
#pragma unroll
        for (int k = 0; k < KK; ++k) {
            const float y = e[k] * inv;
            if (w == 0) sy[k] += y;
#pragma unroll
            for (int j = 0; j < 10; ++j) acc[k][j] = fmaf(y, vC[j], acc[k][j]);
        }
        if (s < 7) {
            float p0 = 0.f, p1 = 0.f, p2 = 0.f, p3 = 0.f;
#pragma unroll
            for (int j = 0; j < 10; ++j) {
                const float vv = vN[j];
                p0 = fmaf(uk[0][j], vv, p0);
                p1 = fmaf(uk[1][j], vv, p1);
                p2 = fmaf(uk[2][j], vv, p2);
                p3 = fmaf(uk[3][j], vv, p3);
            }
            part[cur ^ 1][w][l] = make_float4(p0, p1, p2, p3);
            __syncthreads();
#pragma unroll
            for (int j = 0; j < 10; ++j) vC[j] = vN[j];
            v2C = v2N;
        }
    }

    // epilogue: 4-level shuffle reduce, then atomic from 4 lanes
#pragma unroll
    for (int k = 0; k < KK; ++k) {
#pragma unroll
        for (int j = 0; j < 10; ++j) {
            float val = acc[k][j];
            val += __shfl_down(val, 32);
            val += __shfl_down(val, 16);
            val += __shfl_down(val, 8);
            val += __shfl_down(val, 4);
            if (l < 4) atomicAdd(&accVn[(b * KK + k) * DD + d0 + j], val);
        }
    }
    if (w == 0) {
#pragma unroll
        for (int k = 0; k < KK; ++k) {
            float val = sy[k];
            val += __shfl_down(val, 32);
            val += __shfl_down(val, 16);
            val += __shfl_down(val, 8);
            val += __shfl_down(val, 4);
            if (l < 4) atomicAdd(&accSn[b * KK + k], val);
        }
    }
}

// ---------------------------------------------------------------------------
// A = accV10/(accS10+eps) -> Aout (runs BEFORE mask kernel overwrites slots)
// ---------------------------------------------------------------------------
__global__ __launch_bounds__(256) void copyA_kernel(const float* __restrict__ accV,
                                                    const float* __restrict__ accS,
                                                    float* __restrict__ Aout) {
    int i = blockIdx.x * 256 + threadIdx.x;
    if (i < BB * KK * DD) Aout[i] = accV[i] / (accS[i / DD] + EPS_KM);
}

// ---------------------------------------------------------------------------
// mask = softmax_k(A . Vact). grid (252, BB). Reads A from Aout.
// ---------------------------------------------------------------------------
__global__ __launch_bounds__(256) void mask_kernel(const float* __restrict__ Vact,
                                                   const float* __restrict__ Aout,
                                                   float* __restrict__ mask) {
    __shared__ float sA[KK * DD];
    const int tid = threadIdx.x;
    const int b = blockIdx.y;
    const int n = blockIdx.x * 256 + tid;

    if (tid < KK * DD) sA[tid] = Aout[b * KK * DD + tid];
    __syncthreads();

    const float* Vb = Vact + (size_t)b * DD * NN;
    float d0 = 0.f, d1 = 0.f, d2 = 0.f, d3 = 0.f;
#pragma unroll 8
    for (int d = 0; d < DD; ++d) {
        const float vv = Vb[(size_t)d * NN + n];
        d0 = fmaf(sA[0 * DD + d], vv, d0);
        d1 = fmaf(sA[1 * DD + d], vv, d1);
        d2 = fmaf(sA[2 * DD + d], vv, d2);
        d3 = fmaf(sA[3 * DD + d], vv, d3);
    }
    float m = fmaxf(fmaxf(d0, d1), fmaxf(d2, d3));
    float e0 = __expf(d0 - m), e1 = __expf(d1 - m);
    float e2 = __expf(d2 - m), e3 = __expf(d3 - m);
    float inv = 1.f / (e0 + e1 + e2 + e3);
    float* mb = mask + (size_t)b * KK * NN;
    mb[(size_t)0 * NN + n] = e0 * inv;
    mb[(size_t)1 * NN + n] = e1 * inv;
    mb[(size_t)2 * NN + n] = e2 * inv;
    mb[(size_t)3 * NN + n] = e3 * inv;
}

// ---------------------------------------------------------------------------
extern "C" void kernel_launch(void* const* d_in, const int* in_sizes, int n_in,
                              void* d_out, int out_size, void* d_ws, size_t ws_size,
                              hipStream_t stream) {
    const float* V = (const float*)d_in[0];
    const int* idx = (const int*)d_in[1];

    float* out = (float*)d_out;
    float* mask = out;                                  // BB*KK*NN
    float* Vact = out + (size_t)MASK_FLOATS;            // BB*DD*NN
    float* Aout = Vact + (size_t)BB * DD * NN;          // BB*KK*DD

    // scratch inside mask region (overwritten by mask kernel at the end)
    float* v2 = mask;                 // BB*NN floats
    float* acc = mask + ACC_OFF;      // 11 slots of SLOT_FLOATS
    auto accV = [&](int slot) { return acc + (size_t)slot * SLOT_FLOATS; };
    auto accS = [&](int slot) { return acc + (size_t)slot * SLOT_FLOATS + BB * KK * DD; };

    // zero slots 1..10
    zero_kernel<<<dim3((N_ITERS * SLOT_FLOATS + 255) / 256), dim3(256), 0, stream>>>(
        accV(1), N_ITERS * SLOT_FLOATS);
    tanhv2_kernel<<<dim3(NQ / 256, BB), dim3(256), 0, stream>>>(
        (const float4*)V, (float4*)Vact, (float4*)v2);
    init_kernel<<<dim3(1), dim3(256), 0, stream>>>(V, idx, accV(0), accS(0));

    for (int it = 0; it < N_ITERS; ++it) {
        km_iter_kernel<<<dim3(126, BB), dim3(256), 0, stream>>>(
            Vact, v2, accV(it), accS(it), accV(it + 1), accS(it + 1));
    }

    copyA_kernel<<<dim3(10), dim3(256), 0, stream>>>(accV(N_ITERS), accS(N_ITERS), Aout);
    mask_kernel<<<dim3(NN / 256, BB), dim3(256), 0, stream>>>(Vact, Aout, mask);
}